// Round 3
// baseline (317.263 us; speedup 1.0000x reference)
//
#include <hip/hip_runtime.h>
#include <stdint.h>

typedef __attribute__((ext_vector_type(8))) short s16x8;
typedef __attribute__((ext_vector_type(4))) float f32x4;

__device__ __forceinline__ unsigned short f2bf(float f) {
  unsigned int u = __float_as_uint(f);
  u += 0x7fffu + ((u >> 16) & 1u);
  return (unsigned short)(u >> 16);
}
__device__ __forceinline__ float bf2f(unsigned short h) {
  return __uint_as_float(((unsigned int)h) << 16);
}
// exact hi/lo split: hi = truncated bf16 (f - bf2f(hi) is exact), lo = rounded residual
__device__ __forceinline__ unsigned short hi_trunc(float f) {
  return (unsigned short)(__float_as_uint(f) >> 16);
}
__device__ __forceinline__ f32x4 mfma16(s16x8 a, s16x8 b, f32x4 c) {
  return __builtin_amdgcn_mfma_f32_16x16x32_bf16(a, b, c, 0, 0, 0);
}

// ---------------- attention kernel: one block per batch ----------------
// No LDS for K: QK^T B-fragments load direct global->reg (32 B/lane chunks).
// LDS (40960 B -> 4 blocks/CU, matches VGPR cap):
//   Vt [256 e][64 t] bf16, byte = e*128 + ((2t) ^ ((e&7)<<4))      32768 B
//   P  [64][64]     bf16, byte = 32768 + r*128 + ((2c) ^ ((r&7)<<4)) 8192 B
//   epilogue reuses bytes 0..32767 as X[64][128] fp32 (XOR-swizzled)
// V^T staging overlaps the QK phases (LDS otherwise idle there); barriers: 5.
__global__ __launch_bounds__(256, 4) void attn_kernel(
    const float* __restrict__ Vg, const float* __restrict__ Kg,
    const float* __restrict__ Qg, float* __restrict__ attn_out,
    unsigned short* __restrict__ xb /* bf16 x = attn+q, may be null */) {
  __shared__ __align__(16) char smem[40960];
  char* PLB = smem + 32768;

  const int b = blockIdx.x;
  const int tid = threadIdx.x;
  const int lane = tid & 63;
  const int w = tid >> 6;  // wave id: owns S/A rows 16w..16w+15
  const int n = lane & 15;
  const int q = lane >> 4;

  const float* Qb = Qg + (size_t)b * 64 * 256;
  const float* Kb = Kg + (size_t)b * 64 * 256;
  const float* Vb = Vg + (size_t)b * 64 * 256;

  const int ve = tid & 127;   // V staging: this thread's e (within half)
  const int vt0 = tid >> 7;   // and base t-group parity

  f32x4 accS[4];
#pragma unroll
  for (int c = 0; c < 4; ++c) accS[c] = f32x4{0.f, 0.f, 0.f, 0.f};

  // ---- S = Q K^T (fragments direct from global), V^T staged under it ----
  for (int ph = 0; ph < 2; ++ph) {
    const int e0 = ph * 128;
    // issue V column-gathers for this e-half early; latency hides under MFMAs
    float vr[4][8];
#pragma unroll
    for (int i = 0; i < 4; ++i) {
      int tg = i * 2 + vt0;
#pragma unroll
      for (int j = 0; j < 8; ++j) vr[i][j] = Vb[(tg * 8 + j) * 256 + e0 + ve];
    }
#pragma unroll
    for (int kk = 0; kk < 4; ++kk) {
      const int cb = kk * 32 + q * 8;
      const float* qsrc = Qb + (16 * w + n) * 256 + e0 + cb;
      float4 q0 = *(const float4*)qsrc;
      float4 q1 = *(const float4*)(qsrc + 4);
      float4 k0[4], k1[4];
#pragma unroll
      for (int c = 0; c < 4; ++c) {
        const float* ksrc = Kb + (16 * c + n) * 256 + e0 + cb;
        k0[c] = *(const float4*)ksrc;
        k1[c] = *(const float4*)(ksrc + 4);
      }
      float qa[8] = {q0.x, q0.y, q0.z, q0.w, q1.x, q1.y, q1.z, q1.w};
      s16x8 qh, ql;
#pragma unroll
      for (int j = 0; j < 8; ++j) {
        unsigned short h = hi_trunc(qa[j]);
        qh[j] = (short)h;
        ql[j] = (short)f2bf(qa[j] - bf2f(h));
      }
#pragma unroll
      for (int c = 0; c < 4; ++c) {
        float ka[8] = {k0[c].x, k0[c].y, k0[c].z, k0[c].w,
                       k1[c].x, k1[c].y, k1[c].z, k1[c].w};
        s16x8 kh, kl;
#pragma unroll
        for (int j = 0; j < 8; ++j) {
          unsigned short h = hi_trunc(ka[j]);
          kh[j] = (short)h;
          kl[j] = (short)f2bf(ka[j] - bf2f(h));
        }
        accS[c] = mfma16(qh, kh, accS[c]);
        accS[c] = mfma16(qh, kl, accS[c]);
        accS[c] = mfma16(ql, kh, accS[c]);
      }
    }
    // convert + write V^T half to LDS (16-B granules, conflict-free swizzle)
#pragma unroll
    for (int i = 0; i < 4; ++i) {
      int tg = i * 2 + vt0;
      int e = e0 + ve;
      s16x8 pk;
#pragma unroll
      for (int j = 0; j < 8; ++j) pk[j] = (short)f2bf(vr[i][j]);
      *(s16x8*)(smem + e * 128 + ((tg * 16) ^ ((e & 7) << 4))) = pk;
    }
  }

  // ---- in-register softmax. lane holds S[16w+4q+r][16c+n] in accS[c][r] ----
  const float scale = 0.125f;
  float p[4][4];
#pragma unroll
  for (int r = 0; r < 4; ++r) {
    float m = -1e30f;
#pragma unroll
    for (int c = 0; c < 4; ++c) m = fmaxf(m, accS[c][r]);
#pragma unroll
    for (int mk = 1; mk < 16; mk <<= 1) m = fmaxf(m, __shfl_xor(m, mk, 64));
    float s = 0.f;
#pragma unroll
    for (int c = 0; c < 4; ++c) {
      float e = __expf((accS[c][r] - m) * scale);
      p[c][r] = e;
      s += e;
    }
#pragma unroll
    for (int mk = 1; mk < 16; mk <<= 1) s += __shfl_xor(s, mk, 64);
    float inv = 1.0f / s;
#pragma unroll
    for (int c = 0; c < 4; ++c) p[c][r] *= inv;
  }

  // ---- P to LDS (wave-local rows; read back by same wave) ----
#pragma unroll
  for (int r = 0; r < 4; ++r) {
    int row = 16 * w + 4 * q + r;
    int sw = (row & 7) << 4;
#pragma unroll
    for (int c = 0; c < 4; ++c)
      *(unsigned short*)(PLB + row * 128 + ((2 * (16 * c + n)) ^ sw)) =
          f2bf(p[c][r]);
  }
  __syncthreads();  // Vt writes (all waves) visible

  // ---- A = P V via MFMA, single cluster: 2 ks x 16 c ----
  f32x4 accA[16];
#pragma unroll
  for (int c = 0; c < 16; ++c) accA[c] = f32x4{0.f, 0.f, 0.f, 0.f};
  __builtin_amdgcn_s_setprio(1);
#pragma unroll
  for (int ks = 0; ks < 2; ++ks) {
    const int cb = (ks * 32 + q * 8) * 2;
    const int sw = (n & 7) << 4;
    s16x8 af = *(const s16x8*)(PLB + (16 * w + n) * 128 + (cb ^ sw));
#pragma unroll
    for (int c = 0; c < 16; ++c) {
      int row = 16 * c + n;
      s16x8 bf = *(const s16x8*)(smem + row * 128 + (cb ^ sw));
      accA[c] = mfma16(af, bf, accA[c]);
    }
  }
  __builtin_amdgcn_s_setprio(0);

  // ---- epilogue ----
  if (xb) {
    // 2-pass fp32 transpose through LDS: exact attention + x = attn+q, all
    // global traffic coalesced (float4 Q loads, float4 attn stores, 8-B xb).
#pragma unroll
    for (int h = 0; h < 2; ++h) {
      __syncthreads();  // previous LDS users (PV reads / pass-0 reads) done
#pragma unroll
      for (int r = 0; r < 4; ++r) {
        int t = 16 * w + 4 * q + r;
        int sw = (t & 7) << 4;
#pragma unroll
        for (int c8 = 0; c8 < 8; ++c8) {
          int el = 16 * c8 + n;  // e - 128*h
          *(float*)(smem + t * 512 + ((el * 4) ^ sw)) = accA[h * 8 + c8][r];
        }
      }
      __syncthreads();
#pragma unroll
      for (int i = 0; i < 8; ++i) {
        int f4 = i * 256 + tid;
        int row = f4 >> 5;  // 32 float4 per 128-wide row
        int col4 = f4 & 31;
        int e = h * 128 + col4 * 4;
        float4 av = *(const float4*)(smem + row * 512 + ((col4 * 16) ^ ((row & 7) << 4)));
        float4 qv = *(const float4*)(Qb + row * 256 + e);
        size_t base = ((size_t)b * 64 + row) * 256 + e;
        *(float4*)(attn_out + base) = av;
        ushort4 o;
        o.x = f2bf(av.x + qv.x);
        o.y = f2bf(av.y + qv.y);
        o.z = f2bf(av.z + qv.z);
        o.w = f2bf(av.w + qv.w);
        *(ushort4*)(xb + base) = o;
      }
    }
  } else {
    // fallback: direct strided stores
#pragma unroll
    for (int r = 0; r < 4; ++r) {
      int t = 16 * w + 4 * q + r;
      size_t base = ((size_t)b * 64 + t) * 256;
#pragma unroll
      for (int c = 0; c < 16; ++c) attn_out[base + 16 * c + n] = accA[c][r];
    }
  }
}

// ---------------- W_ff fp32 -> bf16 ----------------
__global__ __launch_bounds__(256) void w2b_kernel(const float* __restrict__ W,
                                                  unsigned short* __restrict__ Wb) {
  int i = blockIdx.x * 256 + threadIdx.x;  // one float4 each, grid covers exactly
  float4 v = ((const float4*)W)[i];
  ushort4 o;
  o.x = f2bf(v.x); o.y = f2bf(v.y); o.z = f2bf(v.z); o.w = f2bf(v.w);
  ((ushort4*)Wb)[i] = o;
}

// ---------------- FF GEMM: out_part = x @ W^T, 64x64 tiles, K-split ----------------
template <bool USE_XB>
__global__ __launch_bounds__(256) void ff_kernel(
    const unsigned short* __restrict__ xb, const float* __restrict__ attn,
    const float* __restrict__ query, const unsigned short* __restrict__ Wb,
    float* __restrict__ part, int kchunk) {
  __shared__ __align__(16) unsigned short As[64 * 72];
  __shared__ __align__(16) unsigned short Bs[64 * 72];
  const int tid = threadIdx.x;
  const int lane = tid & 63, w = tid >> 6, n = lane & 15, q = lane >> 4;
  const int m0 = blockIdx.x * 64;
  const int n0 = blockIdx.y * 64;
  const int k0 = blockIdx.z * kchunk;

  f32x4 acc[4];
#pragma unroll
  for (int c = 0; c < 4; ++c) acc[c] = f32x4{0.f, 0.f, 0.f, 0.f};

  const int srow = tid >> 3;  // 0..31
  const int scol = (tid & 7) * 8;

  for (int kk = 0; kk < kchunk; kk += 64) {
#pragma unroll
    for (int rr = 0; rr < 2; ++rr) {
      int row = rr * 32 + srow;
      size_t ga = (size_t)(m0 + row) * 16384 + k0 + kk + scol;
      if (USE_XB) {
        *(uint4*)(As + row * 72 + scol) = *(const uint4*)(xb + ga);
      } else {
        float4 a0 = *(const float4*)(attn + ga);
        float4 a1 = *(const float4*)(attn + ga + 4);
        float4 q0 = *(const float4*)(query + ga);
        float4 q1 = *(const float4*)(query + ga + 4);
        ushort4 h0, h1;
        h0.x = f2bf(a0.x + q0.x); h0.y = f2bf(a0.y + q0.y);
        h0.z = f2bf(a0.z + q0.z); h0.w = f2bf(a0.w + q0.w);
        h1.x = f2bf(a1.x + q1.x); h1.y = f2bf(a1.y + q1.y);
        h1.z = f2bf(a1.z + q1.z); h1.w = f2bf(a1.w + q1.w);
        *(ushort4*)(As + row * 72 + scol) = h0;
        *(ushort4*)(As + row * 72 + scol + 4) = h1;
      }
      size_t gw = (size_t)(n0 + row) * 16384 + k0 + kk + scol;
      *(uint4*)(Bs + row * 72 + scol) = *(const uint4*)(Wb + gw);
    }
    __syncthreads();
#pragma unroll
    for (int ks = 0; ks < 2; ++ks) {
      const int colb = ks * 32 + q * 8;
      s16x8 af = *(const s16x8*)(As + (16 * w + n) * 72 + colb);
#pragma unroll
      for (int c = 0; c < 4; ++c) {
        s16x8 bf = *(const s16x8*)(Bs + (16 * c + n) * 72 + colb);
        acc[c] = mfma16(af, bf, acc[c]);
      }
    }
    __syncthreads();
  }
#pragma unroll
  for (int r = 0; r < 4; ++r) {
    int m = m0 + 16 * w + 4 * q + r;
#pragma unroll
    for (int c = 0; c < 4; ++c) {
      int nn = n0 + 16 * c + n;
      part[((size_t)blockIdx.z * 2048 + m) * 256 + nn] = acc[c][r];
    }
  }
}

// ---------------- reduce K-split partials + bias + ReLU ----------------
__global__ __launch_bounds__(256) void relu_kernel(const float* __restrict__ part,
                                                   const float* __restrict__ bias,
                                                   float* __restrict__ out, int KS) {
  int idx = blockIdx.x * 256 + threadIdx.x;
  float s = bias[idx & 255];
  for (int ks = 0; ks < KS; ++ks) s += part[(size_t)ks * 2048 * 256 + idx];
  out[idx] = fmaxf(s, 0.f);
}

extern "C" void kernel_launch(void* const* d_in, const int* in_sizes, int n_in,
                              void* d_out, int out_size, void* d_ws, size_t ws_size,
                              hipStream_t stream) {
  const float* value = (const float*)d_in[0];
  const float* key   = (const float*)d_in[1];
  const float* query = (const float*)d_in[2];
  // d_in[3] = mask, unused by the block
  const float* W_ff  = (const float*)d_in[4];
  const float* b_ff  = (const float*)d_in[5];

  float* out  = (float*)d_out;
  float* attn = out + (size_t)2048 * 256;  // outputs: (out, attention) concatenated

  const int KS = 4;
  const size_t wb_bytes   = (size_t)256 * 16384 * 2;      // 8 MB bf16 W
  const size_t part_bytes = (size_t)KS * 2048 * 256 * 4;  // 8 MB fp32 partials
  const size_t xb_bytes   = (size_t)2048 * 64 * 256 * 2;  // 64 MB bf16 x
  unsigned short* Wb = (unsigned short*)d_ws;
  float* part = (float*)((char*)d_ws + wb_bytes);
  bool use_xb = ws_size >= wb_bytes + part_bytes + xb_bytes;
  unsigned short* xb =
      use_xb ? (unsigned short*)((char*)d_ws + wb_bytes + part_bytes) : nullptr;

  w2b_kernel<<<4096, 256, 0, stream>>>(W_ff, Wb);
  attn_kernel<<<2048, 256, 0, stream>>>(value, key, query, attn, xb);
  dim3 gb(32, 4, KS);
  if (use_xb)
    ff_kernel<true><<<gb, 256, 0, stream>>>(xb, nullptr, nullptr, Wb, part, 16384 / KS);
  else
    ff_kernel<false><<<gb, 256, 0, stream>>>(nullptr, attn, query, Wb, part, 16384 / KS);
  relu_kernel<<<2048, 256, 0, stream>>>(part, b_ff, out, KS);
}

// Round 4
// 292.021 us; speedup vs baseline: 1.0864x; 1.0864x over previous
//
#include <hip/hip_runtime.h>
#include <stdint.h>

typedef __attribute__((ext_vector_type(8))) short s16x8;
typedef __attribute__((ext_vector_type(4))) float f32x4;

__device__ __forceinline__ unsigned short f2bf(float f) {
  unsigned int u = __float_as_uint(f);
  u += 0x7fffu + ((u >> 16) & 1u);
  return (unsigned short)(u >> 16);
}
__device__ __forceinline__ float bf2f(unsigned short h) {
  return __uint_as_float(((unsigned int)h) << 16);
}
// exact hi/lo split: hi = truncated bf16 (f - bf2f(hi) is exact), lo = rounded residual
__device__ __forceinline__ unsigned short hi_trunc(float f) {
  return (unsigned short)(__float_as_uint(f) >> 16);
}
__device__ __forceinline__ f32x4 mfma16(s16x8 a, s16x8 b, f32x4 c) {
  return __builtin_amdgcn_mfma_f32_16x16x32_bf16(a, b, c, 0, 0, 0);
}

// Vq write: thread owns e-pair (ep2, ep2+1) x t-range tg*8..tg*8+7 of one e-quarter.
// Layout: row e (64 rows), byte = e*128 + ((2t) ^ (((e>>1)&7)<<4)).
__device__ __forceinline__ void write_vq(char* VqB, int ep2, int tg, const float2* g) {
  s16x8 lo, hi;
#pragma unroll
  for (int j = 0; j < 8; ++j) {
    lo[j] = (short)f2bf(g[j].x);
    hi[j] = (short)f2bf(g[j].y);
  }
  *(s16x8*)(VqB + ep2 * 128 + ((16 * tg) ^ (((ep2 >> 1) & 7) << 4))) = lo;
  *(s16x8*)(VqB + (ep2 + 1) * 128 + ((16 * tg) ^ (((ep2 >> 1) & 7) << 4))) = hi;
}

// ---------------- attention kernel: one block per batch ----------------
// Direct global->reg K fragments (no K LDS, no K barriers).
// LDS 16384 B: Vq [64 e][64 t] bf16 swizzled @0 (8 KB), P [64][64] bf16 @8192 (8 KB).
// PV in four e-quarters (accA = 16 regs); V gathers issued 1-2 quarters ahead;
// per-quarter strided epilogue (64-B contiguous granules per instruction).
__global__ __launch_bounds__(256) void attn_kernel(
    const float* __restrict__ Vg, const float* __restrict__ Kg,
    const float* __restrict__ Qg, float* __restrict__ attn_out,
    unsigned short* __restrict__ xb /* bf16 x = attn+q, may be null */) {
  __shared__ __align__(16) char smem[16384];
  char* VqB = smem;
  char* PLB = smem + 8192;

  const int b = blockIdx.x;
  const int tid = threadIdx.x;
  const int lane = tid & 63;
  const int w = tid >> 6;  // wave id: owns S/A rows 16w..16w+15
  const int n = lane & 15;
  const int q = lane >> 4;

  const float* Qb = Qg + (size_t)b * 64 * 256;
  const float* Kb = Kg + (size_t)b * 64 * 256;
  const float* Vb = Vg + (size_t)b * 64 * 256;

  const int ep2 = (tid & 31) * 2;  // e-pair within quarter (0..62)
  const int tg = tid >> 5;         // 0..7: t = tg*8..tg*8+7

  f32x4 accS[4];
#pragma unroll
  for (int c = 0; c < 4; ++c) accS[c] = f32x4{0.f, 0.f, 0.f, 0.f};

  // ---- S = Q K^T: fragments direct from global, hi/lo bf16 split ----
#pragma unroll
  for (int ph = 0; ph < 2; ++ph) {
    const int e0 = ph * 128;
#pragma unroll
    for (int kk = 0; kk < 4; ++kk) {
      const int cb = kk * 32 + q * 8;
      const float* qsrc = Qb + (16 * w + n) * 256 + e0 + cb;
      float4 q0 = *(const float4*)qsrc;
      float4 q1 = *(const float4*)(qsrc + 4);
      float4 k0[4], k1[4];
#pragma unroll
      for (int c = 0; c < 4; ++c) {
        const float* ksrc = Kb + (16 * c + n) * 256 + e0 + cb;
        k0[c] = *(const float4*)ksrc;
        k1[c] = *(const float4*)(ksrc + 4);
      }
      float qa[8] = {q0.x, q0.y, q0.z, q0.w, q1.x, q1.y, q1.z, q1.w};
      s16x8 qh, ql;
#pragma unroll
      for (int j = 0; j < 8; ++j) {
        unsigned short h = hi_trunc(qa[j]);
        qh[j] = (short)h;
        ql[j] = (short)f2bf(qa[j] - bf2f(h));
      }
#pragma unroll
      for (int c = 0; c < 4; ++c) {
        float ka[8] = {k0[c].x, k0[c].y, k0[c].z, k0[c].w,
                       k1[c].x, k1[c].y, k1[c].z, k1[c].w};
        s16x8 kh, kl;
#pragma unroll
        for (int j = 0; j < 8; ++j) {
          unsigned short h = hi_trunc(ka[j]);
          kh[j] = (short)h;
          kl[j] = (short)f2bf(ka[j] - bf2f(h));
        }
        accS[c] = mfma16(qh, kh, accS[c]);
        accS[c] = mfma16(qh, kl, accS[c]);
        accS[c] = mfma16(ql, kh, accS[c]);
      }
    }
    if (ph == 0) {
      // nothing: keep load order Q/K(ph0) -> V(q0,q1) -> Q/K(ph1)
    }
  }

  // ---- V gathers for quarters 0,1 (issued here; latency hides under softmax) ----
  float2 g0[8], g1[8];
#pragma unroll
  for (int j = 0; j < 8; ++j) g0[j] = *(const float2*)(Vb + (tg * 8 + j) * 256 + 0 + ep2);
#pragma unroll
  for (int j = 0; j < 8; ++j) g1[j] = *(const float2*)(Vb + (tg * 8 + j) * 256 + 64 + ep2);

  // ---- in-register softmax. lane holds S[16w+4q+r][16c+n] in accS[c][r] ----
  const float scale = 0.125f;
  float p[4][4];
#pragma unroll
  for (int r = 0; r < 4; ++r) {
    float m = -1e30f;
#pragma unroll
    for (int c = 0; c < 4; ++c) m = fmaxf(m, accS[c][r]);
#pragma unroll
    for (int mk = 1; mk < 16; mk <<= 1) m = fmaxf(m, __shfl_xor(m, mk, 64));
    float s = 0.f;
#pragma unroll
    for (int c = 0; c < 4; ++c) {
      float e = __expf((accS[c][r] - m) * scale);
      p[c][r] = e;
      s += e;
    }
#pragma unroll
    for (int mk = 1; mk < 16; mk <<= 1) s += __shfl_xor(s, mk, 64);
    float inv = 1.0f / s;
#pragma unroll
    for (int c = 0; c < 4; ++c) p[c][r] *= inv;
  }

  // ---- P to LDS (wave-local rows; read back by same wave) ----
#pragma unroll
  for (int r = 0; r < 4; ++r) {
    int row = 16 * w + 4 * q + r;
    int sw = (row & 7) << 4;
#pragma unroll
    for (int c = 0; c < 4; ++c)
      *(unsigned short*)(PLB + row * 128 + ((2 * (16 * c + n)) ^ sw)) =
          f2bf(p[c][r]);
  }

  // ---- stage V quarter 0, then loop quarters ----
  write_vq(VqB, ep2, tg, g0);
  __syncthreads();

  float2 g2[8], g3[8];
#pragma unroll
  for (int qi = 0; qi < 4; ++qi) {
    // issue gather for quarter qi+2 (in flight across this quarter's compute)
    if (qi == 0) {
#pragma unroll
      for (int j = 0; j < 8; ++j)
        g2[j] = *(const float2*)(Vb + (tg * 8 + j) * 256 + 128 + ep2);
    }
    if (qi == 1) {
#pragma unroll
      for (int j = 0; j < 8; ++j)
        g3[j] = *(const float2*)(Vb + (tg * 8 + j) * 256 + 192 + ep2);
    }

    // PV for this e-quarter
    f32x4 accA[4];
#pragma unroll
    for (int c = 0; c < 4; ++c) accA[c] = f32x4{0.f, 0.f, 0.f, 0.f};
    __builtin_amdgcn_s_setprio(1);
#pragma unroll
    for (int ks = 0; ks < 2; ++ks) {
      const int cb = (ks * 32 + q * 8) * 2;
      s16x8 af = *(const s16x8*)(PLB + (16 * w + n) * 128 + (cb ^ ((n & 7) << 4)));
#pragma unroll
      for (int c = 0; c < 4; ++c) {
        int row = 16 * c + n;
        s16x8 bf = *(const s16x8*)(VqB + row * 128 + (cb ^ (((row >> 1) & 7) << 4)));
        accA[c] = mfma16(af, bf, accA[c]);
      }
    }
    __builtin_amdgcn_s_setprio(0);

    // epilogue for this quarter: strided stores (64-B contiguous granules/instr)
#pragma unroll
    for (int r = 0; r < 4; ++r) {
      int t = 16 * w + 4 * q + r;
      const float* qrow = Qb + t * 256 + qi * 64;
      size_t base = ((size_t)b * 64 + t) * 256 + qi * 64;
#pragma unroll
      for (int c = 0; c < 4; ++c) {
        int e = 16 * c + n;
        float aval = accA[c][r];
        attn_out[base + e] = aval;
        if (xb) xb[base + e] = f2bf(aval + qrow[e]);
      }
    }

    if (qi < 3) {
      __syncthreads();  // all waves done reading Vq
      if (qi == 0) write_vq(VqB, ep2, tg, g1);
      if (qi == 1) write_vq(VqB, ep2, tg, g2);
      if (qi == 2) write_vq(VqB, ep2, tg, g3);
      __syncthreads();  // Vq(i+1) visible
    }
  }
}

// ---------------- W_ff fp32 -> bf16 ----------------
__global__ __launch_bounds__(256) void w2b_kernel(const float* __restrict__ W,
                                                  unsigned short* __restrict__ Wb) {
  int i = blockIdx.x * 256 + threadIdx.x;  // one float4 each, grid covers exactly
  float4 v = ((const float4*)W)[i];
  ushort4 o;
  o.x = f2bf(v.x); o.y = f2bf(v.y); o.z = f2bf(v.z); o.w = f2bf(v.w);
  ((ushort4*)Wb)[i] = o;
}

// ---------------- FF GEMM: out_part = x @ W^T, 64x64 tiles, K-split ----------------
template <bool USE_XB>
__global__ __launch_bounds__(256) void ff_kernel(
    const unsigned short* __restrict__ xb, const float* __restrict__ attn,
    const float* __restrict__ query, const unsigned short* __restrict__ Wb,
    float* __restrict__ part, int kchunk) {
  __shared__ __align__(16) unsigned short As[64 * 72];
  __shared__ __align__(16) unsigned short Bs[64 * 72];
  const int tid = threadIdx.x;
  const int lane = tid & 63, w = tid >> 6, n = lane & 15, q = lane >> 4;
  const int m0 = blockIdx.x * 64;
  const int n0 = blockIdx.y * 64;
  const int k0 = blockIdx.z * kchunk;

  f32x4 acc[4];
#pragma unroll
  for (int c = 0; c < 4; ++c) acc[c] = f32x4{0.f, 0.f, 0.f, 0.f};

  const int srow = tid >> 3;  // 0..31
  const int scol = (tid & 7) * 8;

  for (int kk = 0; kk < kchunk; kk += 64) {
#pragma unroll
    for (int rr = 0; rr < 2; ++rr) {
      int row = rr * 32 + srow;
      size_t ga = (size_t)(m0 + row) * 16384 + k0 + kk + scol;
      if (USE_XB) {
        *(uint4*)(As + row * 72 + scol) = *(const uint4*)(xb + ga);
      } else {
        float4 a0 = *(const float4*)(attn + ga);
        float4 a1 = *(const float4*)(attn + ga + 4);
        float4 q0 = *(const float4*)(query + ga);
        float4 q1 = *(const float4*)(query + ga + 4);
        ushort4 h0, h1;
        h0.x = f2bf(a0.x + q0.x); h0.y = f2bf(a0.y + q0.y);
        h0.z = f2bf(a0.z + q0.z); h0.w = f2bf(a0.w + q0.w);
        h1.x = f2bf(a1.x + q1.x); h1.y = f2bf(a1.y + q1.y);
        h1.z = f2bf(a1.z + q1.z); h1.w = f2bf(a1.w + q1.w);
        *(ushort4*)(As + row * 72 + scol) = h0;
        *(ushort4*)(As + row * 72 + scol + 4) = h1;
      }
      size_t gw = (size_t)(n0 + row) * 16384 + k0 + kk + scol;
      *(uint4*)(Bs + row * 72 + scol) = *(const uint4*)(Wb + gw);
    }
    __syncthreads();
#pragma unroll
    for (int ks = 0; ks < 2; ++ks) {
      const int colb = ks * 32 + q * 8;
      s16x8 af = *(const s16x8*)(As + (16 * w + n) * 72 + colb);
#pragma unroll
      for (int c = 0; c < 4; ++c) {
        s16x8 bf = *(const s16x8*)(Bs + (16 * c + n) * 72 + colb);
        acc[c] = mfma16(af, bf, acc[c]);
      }
    }
    __syncthreads();
  }
#pragma unroll
  for (int r = 0; r < 4; ++r) {
    int m = m0 + 16 * w + 4 * q + r;
#pragma unroll
    for (int c = 0; c < 4; ++c) {
      int nn = n0 + 16 * c + n;
      part[((size_t)blockIdx.z * 2048 + m) * 256 + nn] = acc[c][r];
    }
  }
}

// ---------------- reduce K-split partials + bias + ReLU ----------------
__global__ __launch_bounds__(256) void relu_kernel(const float* __restrict__ part,
                                                   const float* __restrict__ bias,
                                                   float* __restrict__ out, int KS) {
  int idx = blockIdx.x * 256 + threadIdx.x;
  float s = bias[idx & 255];
  for (int ks = 0; ks < KS; ++ks) s += part[(size_t)ks * 2048 * 256 + idx];
  out[idx] = fmaxf(s, 0.f);
}

extern "C" void kernel_launch(void* const* d_in, const int* in_sizes, int n_in,
                              void* d_out, int out_size, void* d_ws, size_t ws_size,
                              hipStream_t stream) {
  const float* value = (const float*)d_in[0];
  const float* key   = (const float*)d_in[1];
  const float* query = (const float*)d_in[2];
  // d_in[3] = mask, unused by the block
  const float* W_ff  = (const float*)d_in[4];
  const float* b_ff  = (const float*)d_in[5];

  float* out  = (float*)d_out;
  float* attn = out + (size_t)2048 * 256;  // outputs: (out, attention) concatenated

  const int KS = 4;
  const size_t wb_bytes   = (size_t)256 * 16384 * 2;      // 8 MB bf16 W
  const size_t part_bytes = (size_t)KS * 2048 * 256 * 4;  // 8 MB fp32 partials
  const size_t xb_bytes   = (size_t)2048 * 64 * 256 * 2;  // 64 MB bf16 x
  unsigned short* Wb = (unsigned short*)d_ws;
  float* part = (float*)((char*)d_ws + wb_bytes);
  bool use_xb = ws_size >= wb_bytes + part_bytes + xb_bytes;
  unsigned short* xb =
      use_xb ? (unsigned short*)((char*)d_ws + wb_bytes + part_bytes) : nullptr;

  w2b_kernel<<<4096, 256, 0, stream>>>(W_ff, Wb);
  attn_kernel<<<2048, 256, 0, stream>>>(value, key, query, attn, xb);
  dim3 gb(32, 4, KS);
  if (use_xb)
    ff_kernel<true><<<gb, 256, 0, stream>>>(xb, nullptr, nullptr, Wb, part, 16384 / KS);
  else
    ff_kernel<false><<<gb, 256, 0, stream>>>(nullptr, attn, query, Wb, part, 16384 / KS);
  relu_kernel<<<2048, 256, 0, stream>>>(part, b_ff, out, KS);
}

// Round 5
// 285.637 us; speedup vs baseline: 1.1107x; 1.0224x over previous
//
#include <hip/hip_runtime.h>
#include <stdint.h>

typedef __attribute__((ext_vector_type(8))) short s16x8;
typedef __attribute__((ext_vector_type(8))) _Float16 h16x8;
typedef __attribute__((ext_vector_type(4))) float f32x4;

__device__ __forceinline__ unsigned short f2h_bits(float f) {
  union { _Float16 h; unsigned short u; } cv;
  cv.h = (_Float16)f;
  return cv.u;
}
__device__ __forceinline__ unsigned short f2bf(float f) {
  unsigned int u = __float_as_uint(f);
  u += 0x7fffu + ((u >> 16) & 1u);
  return (unsigned short)(u >> 16);
}
__device__ __forceinline__ f32x4 mfma16h(h16x8 a, h16x8 b, f32x4 c) {
  return __builtin_amdgcn_mfma_f32_16x16x32_f16(a, b, c, 0, 0, 0);
}

// Vq write: thread owns e-pair (ep2, ep2+1) x t-range tg*8..tg*8+7 of one e-quarter.
// Layout: row e (64 rows), byte = e*128 + ((2t) ^ (((e>>1)&7)<<4)).
__device__ __forceinline__ void write_vq(char* VqB, int ep2, int tg, const float2* g) {
  s16x8 lo, hi;
#pragma unroll
  for (int j = 0; j < 8; ++j) {
    lo[j] = (short)f2h_bits(g[j].x);
    hi[j] = (short)f2h_bits(g[j].y);
  }
  *(s16x8*)(VqB + ep2 * 128 + ((16 * tg) ^ (((ep2 >> 1) & 7) << 4))) = lo;
  *(s16x8*)(VqB + (ep2 + 1) * 128 + ((16 * tg) ^ (((ep2 >> 1) & 7) << 4))) = hi;
}

// ---------------- attention kernel: one block per batch ----------------
// fp16 pipeline (single MFMA per fragment pair; no hi/lo split).
// LDS 24576 B: Vq double buffer 2 x [64 e][64 t] f16 swizzled @0/@8192,
//              P [64][64] f16 @16384.
// 4 barriers total; quarter epilogue runs after the barrier, overlapping the
// next quarter's MFMAs.
__global__ __launch_bounds__(256) void attn_kernel(
    const float* __restrict__ Vg, const float* __restrict__ Kg,
    const float* __restrict__ Qg, float* __restrict__ attn_out,
    unsigned short* __restrict__ xb /* f16 x = attn+q, may be null */) {
  __shared__ __align__(16) char smem[24576];
  char* PLB = smem + 16384;

  const int b = blockIdx.x;
  const int tid = threadIdx.x;
  const int lane = tid & 63;
  const int w = tid >> 6;  // wave id: owns S/A rows 16w..16w+15
  const int n = lane & 15;
  const int q = lane >> 4;

  const float* Qb = Qg + (size_t)b * 64 * 256;
  const float* Kb = Kg + (size_t)b * 64 * 256;
  const float* Vb = Vg + (size_t)b * 64 * 256;

  const int ep2 = (tid & 31) * 2;  // e-pair within quarter (0..62)
  const int tg = tid >> 5;         // 0..7: t = tg*8..tg*8+7

  f32x4 accS[4];
#pragma unroll
  for (int c = 0; c < 4; ++c) accS[c] = f32x4{0.f, 0.f, 0.f, 0.f};

  // ---- S = Q K^T: fragments direct from global, fp16, single MFMA ----
#pragma unroll
  for (int ph = 0; ph < 2; ++ph) {
    const int e0 = ph * 128;
#pragma unroll
    for (int kk = 0; kk < 4; ++kk) {
      const int cb = kk * 32 + q * 8;
      const float* qsrc = Qb + (16 * w + n) * 256 + e0 + cb;
      float4 q0 = *(const float4*)qsrc;
      float4 q1 = *(const float4*)(qsrc + 4);
      float4 k0[4], k1[4];
#pragma unroll
      for (int c = 0; c < 4; ++c) {
        const float* ksrc = Kb + (16 * c + n) * 256 + e0 + cb;
        k0[c] = *(const float4*)ksrc;
        k1[c] = *(const float4*)(ksrc + 4);
      }
      h16x8 qh;
      qh[0] = (_Float16)q0.x; qh[1] = (_Float16)q0.y;
      qh[2] = (_Float16)q0.z; qh[3] = (_Float16)q0.w;
      qh[4] = (_Float16)q1.x; qh[5] = (_Float16)q1.y;
      qh[6] = (_Float16)q1.z; qh[7] = (_Float16)q1.w;
#pragma unroll
      for (int c = 0; c < 4; ++c) {
        h16x8 kh;
        kh[0] = (_Float16)k0[c].x; kh[1] = (_Float16)k0[c].y;
        kh[2] = (_Float16)k0[c].z; kh[3] = (_Float16)k0[c].w;
        kh[4] = (_Float16)k1[c].x; kh[5] = (_Float16)k1[c].y;
        kh[6] = (_Float16)k1[c].z; kh[7] = (_Float16)k1[c].w;
        accS[c] = mfma16h(qh, kh, accS[c]);
      }
    }
  }

  // ---- V gathers for quarters 0,1 (latency hides under softmax) ----
  float2 g0[8], g1[8];
#pragma unroll
  for (int j = 0; j < 8; ++j) g0[j] = *(const float2*)(Vb + (tg * 8 + j) * 256 + 0 + ep2);
#pragma unroll
  for (int j = 0; j < 8; ++j) g1[j] = *(const float2*)(Vb + (tg * 8 + j) * 256 + 64 + ep2);

  // ---- in-register softmax. lane holds S[16w+4q+r][16c+n] in accS[c][r] ----
  const float scale = 0.125f;
  float p[4][4];
#pragma unroll
  for (int r = 0; r < 4; ++r) {
    float m = -1e30f;
#pragma unroll
    for (int c = 0; c < 4; ++c) m = fmaxf(m, accS[c][r]);
#pragma unroll
    for (int mk = 1; mk < 16; mk <<= 1) m = fmaxf(m, __shfl_xor(m, mk, 64));
    float s = 0.f;
#pragma unroll
    for (int c = 0; c < 4; ++c) {
      float e = __expf((accS[c][r] - m) * scale);
      p[c][r] = e;
      s += e;
    }
#pragma unroll
    for (int mk = 1; mk < 16; mk <<= 1) s += __shfl_xor(s, mk, 64);
    float inv = 1.0f / s;
#pragma unroll
    for (int c = 0; c < 4; ++c) p[c][r] *= inv;
  }

  // ---- P to LDS (f16) ----
#pragma unroll
  for (int r = 0; r < 4; ++r) {
    int row = 16 * w + 4 * q + r;
    int sw = (row & 7) << 4;
#pragma unroll
    for (int c = 0; c < 4; ++c)
      *(unsigned short*)(PLB + row * 128 + ((2 * (16 * c + n)) ^ sw)) =
          f2h_bits(p[c][r]);
  }

  // ---- stage V quarter 0 into buf0 ----
  write_vq(smem, ep2, tg, g0);
  __syncthreads();

  float2 g2[8], g3[8];
  f32x4 accA[4];
#pragma unroll
  for (int qi = 0; qi < 4; ++qi) {
    char* VqB = smem + (qi & 1) * 8192;
    // issue gather for quarter qi+2 (in flight across this quarter's compute)
    if (qi == 0) {
#pragma unroll
      for (int j = 0; j < 8; ++j)
        g2[j] = *(const float2*)(Vb + (tg * 8 + j) * 256 + 128 + ep2);
    }
    if (qi == 1) {
#pragma unroll
      for (int j = 0; j < 8; ++j)
        g3[j] = *(const float2*)(Vb + (tg * 8 + j) * 256 + 192 + ep2);
    }

    // PV for this e-quarter
#pragma unroll
    for (int c = 0; c < 4; ++c) accA[c] = f32x4{0.f, 0.f, 0.f, 0.f};
    __builtin_amdgcn_s_setprio(1);
#pragma unroll
    for (int ks = 0; ks < 2; ++ks) {
      const int cb = (ks * 32 + q * 8) * 2;
      h16x8 af = *(const h16x8*)(PLB + (16 * w + n) * 128 + (cb ^ ((n & 7) << 4)));
#pragma unroll
      for (int c = 0; c < 4; ++c) {
        int row = 16 * c + n;
        h16x8 bf = *(const h16x8*)(VqB + row * 128 + (cb ^ (((row >> 1) & 7) << 4)));
        accA[c] = mfma16h(af, bf, accA[c]);
      }
    }
    __builtin_amdgcn_s_setprio(0);

    if (qi < 3) {
      // stage next quarter into the other buffer; safe: all waves finished
      // reading it one quarter ago (previous barrier)
      char* VqN = smem + ((qi + 1) & 1) * 8192;
      if (qi == 0) write_vq(VqN, ep2, tg, g1);
      if (qi == 1) write_vq(VqN, ep2, tg, g2);
      if (qi == 2) write_vq(VqN, ep2, tg, g3);
      __syncthreads();
    }

    // epilogue for this quarter (after barrier: overlaps next quarter's MFMAs)
#pragma unroll
    for (int r = 0; r < 4; ++r) {
      int t = 16 * w + 4 * q + r;
      const float* qrow = Qb + t * 256 + qi * 64;
      size_t base = ((size_t)b * 64 + t) * 256 + qi * 64;
#pragma unroll
      for (int c = 0; c < 4; ++c) {
        int e = 16 * c + n;
        float aval = accA[c][r];
        attn_out[base + e] = aval;
        if (xb) xb[base + e] = f2h_bits(aval + qrow[e]);
      }
    }
  }
}

// ---------------- W_ff fp32 -> f16 ----------------
__global__ __launch_bounds__(256) void w2b_kernel(const float* __restrict__ W,
                                                  unsigned short* __restrict__ Wb) {
  int i = blockIdx.x * 256 + threadIdx.x;  // one float4 each, grid covers exactly
  float4 v = ((const float4*)W)[i];
  ushort4 o;
  o.x = f2h_bits(v.x); o.y = f2h_bits(v.y); o.z = f2h_bits(v.z); o.w = f2h_bits(v.w);
  ((ushort4*)Wb)[i] = o;
}

// ---------------- FF GEMM: out_part = x @ W^T, 64x64 tiles, K-split ----------------
template <bool USE_XB>
__global__ __launch_bounds__(256) void ff_kernel(
    const unsigned short* __restrict__ xb, const float* __restrict__ attn,
    const float* __restrict__ query, const unsigned short* __restrict__ Wb,
    float* __restrict__ part, int kchunk) {
  __shared__ __align__(16) unsigned short As[64 * 72];
  __shared__ __align__(16) unsigned short Bs[64 * 72];
  const int tid = threadIdx.x;
  const int lane = tid & 63, w = tid >> 6, n = lane & 15, q = lane >> 4;
  const int m0 = blockIdx.x * 64;
  const int n0 = blockIdx.y * 64;
  const int k0 = blockIdx.z * kchunk;

  f32x4 acc[4];
#pragma unroll
  for (int c = 0; c < 4; ++c) acc[c] = f32x4{0.f, 0.f, 0.f, 0.f};

  const int srow = tid >> 3;  // 0..31
  const int scol = (tid & 7) * 8;

  for (int kk = 0; kk < kchunk; kk += 64) {
#pragma unroll
    for (int rr = 0; rr < 2; ++rr) {
      int row = rr * 32 + srow;
      size_t ga = (size_t)(m0 + row) * 16384 + k0 + kk + scol;
      if (USE_XB) {
        *(uint4*)(As + row * 72 + scol) = *(const uint4*)(xb + ga);
      } else {
        float4 a0 = *(const float4*)(attn + ga);
        float4 a1 = *(const float4*)(attn + ga + 4);
        float4 q0 = *(const float4*)(query + ga);
        float4 q1 = *(const float4*)(query + ga + 4);
        ushort4 h0, h1;
        h0.x = f2h_bits(a0.x + q0.x); h0.y = f2h_bits(a0.y + q0.y);
        h0.z = f2h_bits(a0.z + q0.z); h0.w = f2h_bits(a0.w + q0.w);
        h1.x = f2h_bits(a1.x + q1.x); h1.y = f2h_bits(a1.y + q1.y);
        h1.z = f2h_bits(a1.z + q1.z); h1.w = f2h_bits(a1.w + q1.w);
        *(ushort4*)(As + row * 72 + scol) = h0;
        *(ushort4*)(As + row * 72 + scol + 4) = h1;
      }
      size_t gw = (size_t)(n0 + row) * 16384 + k0 + kk + scol;
      *(uint4*)(Bs + row * 72 + scol) = *(const uint4*)(Wb + gw);
    }
    __syncthreads();
#pragma unroll
    for (int ks = 0; ks < 2; ++ks) {
      const int colb = ks * 32 + q * 8;
      h16x8 af = *(const h16x8*)(As + (16 * w + n) * 72 + colb);
#pragma unroll
      for (int c = 0; c < 4; ++c) {
        h16x8 bf = *(const h16x8*)(Bs + (16 * c + n) * 72 + colb);
        acc[c] = mfma16h(af, bf, acc[c]);
      }
    }
    __syncthreads();
  }
#pragma unroll
  for (int r = 0; r < 4; ++r) {
    int m = m0 + 16 * w + 4 * q + r;
#pragma unroll
    for (int c = 0; c < 4; ++c) {
      int nn = n0 + 16 * c + n;
      part[((size_t)blockIdx.z * 2048 + m) * 256 + nn] = acc[c][r];
    }
  }
}

// ---------------- reduce K-split partials + bias + ReLU ----------------
__global__ __launch_bounds__(256) void relu_kernel(const float* __restrict__ part,
                                                   const float* __restrict__ bias,
                                                   float* __restrict__ out, int KS) {
  int idx = blockIdx.x * 256 + threadIdx.x;
  float s = bias[idx & 255];
  for (int ks = 0; ks < KS; ++ks) s += part[(size_t)ks * 2048 * 256 + idx];
  out[idx] = fmaxf(s, 0.f);
}

extern "C" void kernel_launch(void* const* d_in, const int* in_sizes, int n_in,
                              void* d_out, int out_size, void* d_ws, size_t ws_size,
                              hipStream_t stream) {
  const float* value = (const float*)d_in[0];
  const float* key   = (const float*)d_in[1];
  const float* query = (const float*)d_in[2];
  // d_in[3] = mask, unused by the block
  const float* W_ff  = (const float*)d_in[4];
  const float* b_ff  = (const float*)d_in[5];

  float* out  = (float*)d_out;
  float* attn = out + (size_t)2048 * 256;  // outputs: (out, attention) concatenated

  const int KS = 4;
  const size_t wb_bytes   = (size_t)256 * 16384 * 2;      // 8 MB f16 W
  const size_t part_bytes = (size_t)KS * 2048 * 256 * 4;  // 8 MB fp32 partials
  const size_t xb_bytes   = (size_t)2048 * 64 * 256 * 2;  // 64 MB f16 x
  unsigned short* Wb = (unsigned short*)d_ws;
  float* part = (float*)((char*)d_ws + wb_bytes);
  bool use_xb = ws_size >= wb_bytes + part_bytes + xb_bytes;
  unsigned short* xb =
      use_xb ? (unsigned short*)((char*)d_ws + wb_bytes + part_bytes) : nullptr;

  w2b_kernel<<<4096, 256, 0, stream>>>(W_ff, Wb);
  attn_kernel<<<2048, 256, 0, stream>>>(value, key, query, attn, xb);
  dim3 gb(32, 4, KS);
  if (use_xb)
    ff_kernel<true><<<gb, 256, 0, stream>>>(xb, nullptr, nullptr, Wb, part, 16384 / KS);
  else
    ff_kernel<false><<<gb, 256, 0, stream>>>(nullptr, attn, query, Wb, part, 16384 / KS);
  relu_kernel<<<2048, 256, 0, stream>>>(part, b_ff, out, KS);
}